// Round 11
// baseline (154.934 us; speedup 1.0000x reference)
//
#include <hip/hip_runtime.h>
#include <cstdint>
#include <cstddef>

#define N_ENT 40000
#define DDIM  128
#define BSZ   1024
#define NJT   313               // ceil(40000/128)
#define NPART (16 * NJT)        // 5008 written partials
#define NGRID 5120              // padded: 8 XCD groups x 40 t-slots x 16 members

typedef short s16x8 __attribute__((ext_vector_type(8)));
typedef float f32x4 __attribute__((ext_vector_type(4)));

// ws layout (bytes), 256-aligned:
//   0       : partials f32[5008]
//   20480   : tpart    f32[1024]
//   24576   : cnorm    f32[2048]
//   32768   : c_bf     u16[2048*128]   -> end 557,056 B
#define OFF_PART  0
#define OFF_TPART 20480
#define OFF_CNORM 24576
#define OFF_CBF   32768

#define S_CLAMP 15.9423847f      // -ln(2^-23): clip(pred, eps, 1-eps) bound in fp32
#define U_CLAMP 0.159423847f     // S_CLAMP / 100  (s = 100*u)
#define LP_MAX (-1.1920929e-7f)  // ln(fl32(1-1e-7))

__device__ __forceinline__ unsigned short f2bf(float f) {
  uint32_t u = __float_as_uint(f);
  u += 0x7fffu + ((u >> 16) & 1u);   // round-to-nearest-even
  return (unsigned short)(u >> 16);
}

// Prep: c rows only (entity conversion now fused into main's staging).
// 256 blocks, float4 width, two rows per wave (lanes 0..31 row base, 32..63
// row base+1). c = ent[h]+r -> bf16(RNE) + fp32 norm; positive rows also
// compute the exact target-pair fixup tpart = log(pred) - A',
// A' = max(-s, -S_CLAMP) = exactly what main_k adds for that element.
__global__ __launch_bounds__(256) void prep_k(const float* __restrict__ ent,
                                              const int* __restrict__ pos_h,
                                              const int* __restrict__ pos_t,
                                              const int* __restrict__ neg_h,
                                              const float* __restrict__ rpos,
                                              const float* __restrict__ rneg,
                                              const int* __restrict__ l1_flag,
                                              unsigned short* __restrict__ c_bf,
                                              float* __restrict__ cnorm,
                                              float* __restrict__ tpart) {
  const int lane = threadIdx.x & 63, wv = threadIdx.x >> 6;
  const int ih = lane >> 5, il = lane & 31;      // half-index, lane-in-half
  int row = blockIdx.x * 8 + wv * 2 + ih;        // 0..2047
  int br = row >> 10, i = row & 1023;
  int h = br ? neg_h[i] : pos_h[i];
  const float* rs = br ? rneg : rpos;
  float4 e  = reinterpret_cast<const float4*>(ent + (size_t)h * DDIM)[il];
  float4 rv = reinterpret_cast<const float4*>(rs + (size_t)i * DDIM)[il];
  float c0 = e.x + rv.x, c1 = e.y + rv.y, c2 = e.z + rv.z, c3 = e.w + rv.w;
  ushort4 h4; h4.x = f2bf(c0); h4.y = f2bf(c1); h4.z = f2bf(c2); h4.w = f2bf(c3);
  reinterpret_cast<ushort4*>(c_bf + (size_t)row * DDIM)[il] = h4;
  float sq = fmaf(c0, c0, fmaf(c1, c1, fmaf(c2, c2, c3 * c3)));
  #pragma unroll
  for (int m = 1; m <= 16; m <<= 1) sq += __shfl_xor(sq, m);     // within 32-lane half
  if (il == 0) cnorm[row] = sq;
  if (br == 0) {
    int t = pos_t[i];
    float4 et = reinterpret_cast<const float4*>(ent + (size_t)t * DDIM)[il];
    float d0 = c0 - et.x, d1 = c1 - et.y, d2v = c2 - et.z, d3 = c3 - et.w;
    float d2 = fmaf(d0, d0, fmaf(d1, d1, fmaf(d2v, d2v, d3 * d3)));
    float m1 = fabsf(d0) + fabsf(d1) + fabsf(d2v) + fabsf(d3);
    #pragma unroll
    for (int m = 1; m <= 16; m <<= 1) { d2 += __shfl_xor(d2, m); m1 += __shfl_xor(m1, m); }
    if (il == 0) {
      float s = (*l1_flag) ? (100.f / fmaxf(m1, 1e-12f))
                           : (100.f * rsqrtf(fmaxf(d2, 0.f)));   // d2=0 -> inf, clamps ok
      float x  = __expf(-s);
      float L  = log1pf(x);
      float Bt = fminf(-L, LP_MAX);          // exact log(pred)
      float Ap = fmaxf(-s, -S_CLAMP);        // what main_k adds for this element
      tpart[i] = Bt - Ap;
    }
  }
}

// Main: R10 body (63 µs measured) with entity-prep FUSED into staging: B tile
// loaded straight from f32 ent (2 x float4 -> truncation-pack bf16 ->
// swizzled ds_write_b128, c' = c^(row&15)), fp32 row norms computed from the
// same registers into LDS (R5-verified code path). Kills the 40000-row prep
// kernel + ent_bf/enorm HBM round trips; FETCH rises ~7->21 MB but R10 shows
// BW is 1.5% of peak. Truncation (vs RNE) costs ~5e-4 bias on the mean
// (threshold 0.205), saves ~3 µs of packing VALU.
// XCD-aware 1D swizzle: jt = (id&7) + 8*(id>>7); the 16 blocks sharing a
// j-tile all have id == jt (mod 8) -> one XCD -> tile fetched once per L2
// (verified R10: FETCH 41->7 MB). Padded grid 5120; jt>=313 exits pre-barrier.
// One pass/block, 128x128 tile, 2x2 waves, 4x4 MFMA tiles; A frags direct
// from L2-hot c_bf, dbuf over kc. NO fused finalize (R7: device fences at 5k
// blocks cost ~90 µs). 5-inst epilogue in u-units; tpart replaces target check.
__global__ __launch_bounds__(256) void main_k(const unsigned short* __restrict__ c_bf,
                                              const float* __restrict__ ent_f32,
                                              const float* __restrict__ cnorm,
                                              const int* __restrict__ l1_flag,
                                              const int* __restrict__ pos_h,
                                              const int* __restrict__ neg_h,
                                              const float* __restrict__ rpos,
                                              const float* __restrict__ rneg,
                                              float* __restrict__ partials) {
  __shared__ unsigned short smem[128 * 128];    // 32 KB swizzled B tile
  __shared__ float rn[128];                     // fp32 row norms of the tile
  const int id = blockIdx.x;
  const int c8 = id & 7;
  const int q  = id >> 3;
  const int tg = q >> 4;                         // 0..39
  const int mm = q & 15;                         // member 0..15
  const int jt = c8 + tg * 8;                    // 0..319
  if (jt >= NJT) return;                         // block-uniform, pre-barrier
  const int branch = mm & 1;
  const int it = mm >> 1;                        // 0..7
  const int i0 = it * 128, j0 = jt * 128;
  const int tid = threadIdx.x, lane = tid & 63, wv = tid >> 6;
  const int wm = wv >> 1, wn = wv & 1;
  const int r15 = lane & 15, quad = lane >> 4;

  // ---- stage B tile from f32: 2048 chunks of 8 elems, swizzled, + norms ----
  #pragma unroll
  for (int i = 0; i < 8; ++i) {
    int g  = i * 256 + tid;
    int r  = g >> 4;                 // tile row; constant across each 16-lane group
    int cp = g & 15;                 // swizzled chunk col
    int c  = cp ^ (r & 15);          // source chunk col
    int jr = j0 + r; if (jr >= N_ENT) jr = N_ENT - 1;   // clamp; masked in epilogue
    const float4* src = reinterpret_cast<const float4*>(ent_f32 + (size_t)jr * DDIM + c * 8);
    float4 v0 = src[0], v1 = src[1];
    float sq = fmaf(v0.x, v0.x, fmaf(v0.y, v0.y, fmaf(v0.z, v0.z,
               fmaf(v0.w, v0.w, fmaf(v1.x, v1.x, fmaf(v1.y, v1.y,
               fmaf(v1.z, v1.z, v1.w * v1.w)))))));
    #pragma unroll
    for (int m = 1; m <= 8; m <<= 1) sq += __shfl_xor(sq, m);   // within 16-lane group
    if ((lane & 15) == 0) rn[r] = sq;
    // truncation-pack: low address = low half
    uint32_t w0 = (__float_as_uint(v0.x) >> 16) | (__float_as_uint(v0.y) & 0xffff0000u);
    uint32_t w1 = (__float_as_uint(v0.z) >> 16) | (__float_as_uint(v0.w) & 0xffff0000u);
    uint32_t w2 = (__float_as_uint(v1.x) >> 16) | (__float_as_uint(v1.y) & 0xffff0000u);
    uint32_t w3 = (__float_as_uint(v1.z) >> 16) | (__float_as_uint(v1.w) & 0xffff0000u);
    int4 pk; pk.x = (int)w0; pk.y = (int)w1; pk.z = (int)w2; pk.w = (int)w3;
    *reinterpret_cast<int4*>(&smem[g * 8]) = pk;   // 16B-aligned ds_write_b128
  }

  // ---- A fragment pointers + prefetch kc=0; preload cnorm (hide L2 latency) ----
  const unsigned short* Abase = c_bf + ((size_t)(branch << 10) + i0) * DDIM;
  const unsigned short* arow[4];
  #pragma unroll
  for (int tm = 0; tm < 4; ++tm)
    arow[tm] = Abase + (size_t)(wm * 64 + tm * 16 + r15) * DDIM + quad * 8;

  s16x8 av[2][4];
  #pragma unroll
  for (int tm = 0; tm < 4; ++tm)
    av[0][tm] = *reinterpret_cast<const s16x8*>(arow[tm]);

  float cnv[16];
  #pragma unroll
  for (int tm = 0; tm < 4; ++tm)
    #pragma unroll
    for (int r = 0; r < 4; ++r)
      cnv[tm * 4 + r] = cnorm[(branch << 10) + i0 + wm * 64 + tm * 16 + quad * 4 + r];

  f32x4 acc[4][4];
  const f32x4 zf = {0.f, 0.f, 0.f, 0.f};
  #pragma unroll
  for (int a = 0; a < 4; ++a)
    #pragma unroll
    for (int b = 0; b < 4; ++b) acc[a][b] = zf;

  __syncthreads();   // B tile + norms staged (A kc0 + cnorm also landed)

  float en[4];
  #pragma unroll
  for (int tn = 0; tn < 4; ++tn)
    en[tn] = rn[wn * 64 + tn * 16 + r15];

  #pragma unroll
  for (int kc = 0; kc < 4; ++kc) {
    if (kc < 3) {
      #pragma unroll
      for (int tm = 0; tm < 4; ++tm)
        av[(kc + 1) & 1][tm] = *reinterpret_cast<const s16x8*>(arow[tm] + (kc + 1) * 32);
    }
    s16x8 bv[4];
    #pragma unroll
    for (int tn = 0; tn < 4; ++tn) {
      int R  = wn * 64 + tn * 16 + r15;
      int cs = (kc * 4 + quad) ^ r15;
      bv[tn] = *reinterpret_cast<const s16x8*>(&smem[R * 128 + cs * 8]);
    }
    #pragma unroll
    for (int tm = 0; tm < 4; ++tm)
      #pragma unroll
      for (int tn = 0; tn < 4; ++tn)
        acc[tm][tn] = __builtin_amdgcn_mfma_f32_16x16x32_bf16(av[kc & 1][tm], bv[tn], acc[tm][tn], 0, 0, 0);
  }

  // ---- 5-inst epilogue: add, fma, rsqrt, fmin, add (in u-units) ----
  const int l1 = *l1_flag;
  float lsum = 0.f;
  const bool full = (j0 + 128) <= N_ENT;   // block-uniform

  if (!l1) {
    #pragma unroll
    for (int tm = 0; tm < 4; ++tm) {
      if (full) {
        #pragma unroll
        for (int tn = 0; tn < 4; ++tn) {
          float e0 = en[tn];
          #pragma unroll
          for (int r = 0; r < 4; ++r) {
            float u = rsqrtf(fmaf(-2.f, acc[tm][tn][r], cnv[tm * 4 + r] + e0));  // <=0/NaN -> fmin clamps
            lsum += fminf(u, U_CLAMP);
          }
        }
      } else {
        #pragma unroll
        for (int tn = 0; tn < 4; ++tn) {
          int jg = j0 + wn * 64 + tn * 16 + r15;
          if (jg < N_ENT) {
            float e0 = en[tn];
            #pragma unroll
            for (int r = 0; r < 4; ++r) {
              float u = rsqrtf(fmaf(-2.f, acc[tm][tn][r], cnv[tm * 4 + r] + e0));
              lsum += fminf(u, U_CLAMP);
            }
          }
        }
      }
    }
  } else {
    // L1 fallback (dead with this harness's inputs): recompute on the fly.
    const float* rs = branch ? rneg : rpos;
    const int*   hb = branch ? neg_h : pos_h;
    #pragma unroll 1
    for (int tm = 0; tm < 4; ++tm) {
      #pragma unroll 1
      for (int r = 0; r < 4; ++r) {
        int bi = i0 + wm * 64 + tm * 16 + quad * 4 + r;
        int h  = hb[bi];
        #pragma unroll 1
        for (int tn = 0; tn < 4; ++tn) {
          int jg = j0 + wn * 64 + tn * 16 + r15;
          if (jg < N_ENT) {
            const float* cp1 = ent_f32 + (size_t)h * DDIM;
            const float* cp2 = rs + (size_t)bi * DDIM;
            const float* ep  = ent_f32 + (size_t)jg * DDIM;
            float man = 0.f;
            #pragma unroll 1
            for (int d = 0; d < DDIM; ++d) man += fabsf(cp1[d] + cp2[d] - ep[d]);
            float s = 100.f / fmaxf(man, 1e-12f);
            lsum += 0.01f * fminf(s, S_CLAMP);   // same u-unit scale
          }
        }
      }
    }
  }

  // block reduction -> one partial per block (no atomics, no fences)
  #pragma unroll
  for (int m = 32; m; m >>= 1) lsum += __shfl_xor(lsum, m);
  __shared__ float s4[4];
  if (lane == 0) s4[wv] = lsum;
  __syncthreads();
  if (tid == 0)
    partials[jt * 16 + mm] = s4[0] + s4[1] + s4[2] + s4[3];
}

// Parallel finalize: 24 blocks, one element per thread, f32 atomic into the
// memset-zeroed d_out. Blocks [0,20): partials (x 100/(B*N)); [20,24): tpart
// (x -1/(B*N)). ~24 atomics to one address: trivial contention.
__global__ __launch_bounds__(256) void finalize_k(const float* __restrict__ partials,
                                                  const float* __restrict__ tpart,
                                                  float* __restrict__ out) {
  const int b = blockIdx.x, tid = threadIdx.x, lane = tid & 63, wv = tid >> 6;
  const double inv = 1.0 / ((double)BSZ * (double)N_ENT);
  double v = 0.0;
  if (b < 20) {
    int i = b * 256 + tid;
    if (i < NPART) v = (double)partials[i] * (100.0 * inv);
  } else {
    int i = (b - 20) * 256 + tid;
    v = (double)tpart[i] * (-inv);
  }
  #pragma unroll
  for (int m = 32; m; m >>= 1) v += __shfl_xor(v, m);
  __shared__ double sd[4];
  if (lane == 0) sd[wv] = v;
  __syncthreads();
  if (tid == 0) atomicAdd(out, (float)(sd[0] + sd[1] + sd[2] + sd[3]));
}

extern "C" void kernel_launch(void* const* d_in, const int* in_sizes, int n_in,
                              void* d_out, int out_size, void* d_ws, size_t ws_size,
                              hipStream_t stream) {
  const int*   pos_h = (const int*)d_in[0];
  const int*   pos_t = (const int*)d_in[1];
  const int*   neg_h = (const int*)d_in[2];
  // d_in[3] = neg_t_batch (unused by reference)
  const float* rpos  = (const float*)d_in[4];
  const float* rneg  = (const float*)d_in[5];
  const float* ent   = (const float*)d_in[6];
  const int*   l1    = (const int*)d_in[7];

  char* ws = (char*)d_ws;
  float*          partials = (float*)(ws + OFF_PART);
  float*          tpart    = (float*)(ws + OFF_TPART);
  float*          cnorm    = (float*)(ws + OFF_CNORM);
  unsigned short* c_bf     = (unsigned short*)(ws + OFF_CBF);

  hipMemsetAsync(d_out, 0, sizeof(float), stream);   // finalize accumulates atomically

  prep_k<<<256, 256, 0, stream>>>(ent, pos_h, pos_t, neg_h, rpos, rneg, l1,
                                  c_bf, cnorm, tpart);

  main_k<<<NGRID, 256, 0, stream>>>(c_bf, ent, cnorm, l1,
                                    pos_h, neg_h, rpos, rneg, partials);

  finalize_k<<<24, 256, 0, stream>>>(partials, tpart, (float*)d_out);
}

// Round 12
// 143.300 us; speedup vs baseline: 1.0812x; 1.0812x over previous
//
#include <hip/hip_runtime.h>
#include <cstdint>
#include <cstddef>

#define N_ENT 40000
#define DDIM  128
#define BSZ   1024
#define NJT   313               // ceil(40000/128)
#define NPART (16 * NJT)        // 5008 written partials
#define NGRID 5120              // padded: 8 XCD groups x 40 t-slots x 16 members

#define AS1 __attribute__((address_space(1)))
#define AS3 __attribute__((address_space(3)))

typedef short s16x8 __attribute__((ext_vector_type(8)));
typedef float f32x4 __attribute__((ext_vector_type(4)));

// ws layout (bytes), 256-aligned:
//   0       : partials f32[5008]
//   20480   : tpart    f32[1024]
//   24576   : enorm    f32[40000]
//   184576  : cnorm    f32[2048]
//   192768  : c_bf     u16[2048*128]
//   717056  : ent_bf   u16[40000*128]  -> end 10,957,056 B
#define OFF_PART  0
#define OFF_TPART 20480
#define OFF_ENORM 24576
#define OFF_CNORM 184576
#define OFF_CBF   192768
#define OFF_EBF   717056

#define S_CLAMP 15.9423847f      // -ln(2^-23): clip(pred, eps, 1-eps) bound in fp32
#define U_CLAMP 0.159423847f     // S_CLAMP / 100  (s = 100*u)
#define LP_MAX (-1.1920929e-7f)  // ln(fl32(1-1e-7))

__device__ __forceinline__ unsigned short f2bf(float f) {
  uint32_t u = __float_as_uint(f);
  u += 0x7fffu + ((u >> 16) & 1u);   // round-to-nearest-even
  return (unsigned short)(u >> 16);
}

// Skinny prep, float4 width (16 B/lane): two rows per wave, lanes 0..31 ->
// row base, lanes 32..63 -> row base+1. One load chain per wave, fully
// latency-parallel. (R11 showed fusing the entity half into main's staging
// costs ~25 µs of serialized pre-barrier work — async DMA staging wins.)
//  blocks [0,5000): entity rows -> bf16 + fp32 norm.
//  blocks [5000,5256): c rows = ent[h]+r -> bf16 + norm; positive rows also
//    compute the exact target-pair fixup tpart = log(pred) - A',
//    A' = max(-s, -S_CLAMP) = exactly what main_k adds for that element.
__global__ __launch_bounds__(256) void prep_k(const float* __restrict__ ent,
                                              const int* __restrict__ pos_h,
                                              const int* __restrict__ pos_t,
                                              const int* __restrict__ neg_h,
                                              const float* __restrict__ rpos,
                                              const float* __restrict__ rneg,
                                              const int* __restrict__ l1_flag,
                                              unsigned short* __restrict__ ent_bf,
                                              float* __restrict__ enorm,
                                              unsigned short* __restrict__ c_bf,
                                              float* __restrict__ cnorm,
                                              float* __restrict__ tpart) {
  const int lane = threadIdx.x & 63, wv = threadIdx.x >> 6;
  const int ih = lane >> 5, il = lane & 31;      // half-index, lane-in-half
  const int blk = blockIdx.x;
  if (blk < 5000) {
    int row = blk * 8 + wv * 2 + ih;             // 0..39999
    float4 v = reinterpret_cast<const float4*>(ent + (size_t)row * DDIM)[il];
    ushort4 h4; h4.x = f2bf(v.x); h4.y = f2bf(v.y); h4.z = f2bf(v.z); h4.w = f2bf(v.w);
    reinterpret_cast<ushort4*>(ent_bf + (size_t)row * DDIM)[il] = h4;
    float sq = fmaf(v.x, v.x, fmaf(v.y, v.y, fmaf(v.z, v.z, v.w * v.w)));
    #pragma unroll
    for (int m = 1; m <= 16; m <<= 1) sq += __shfl_xor(sq, m);   // within 32-lane half
    if (il == 0) enorm[row] = sq;
  } else {
    int row = (blk - 5000) * 8 + wv * 2 + ih;    // 0..2047
    int br = row >> 10, i = row & 1023;
    int h = br ? neg_h[i] : pos_h[i];
    const float* rs = br ? rneg : rpos;
    float4 e  = reinterpret_cast<const float4*>(ent + (size_t)h * DDIM)[il];
    float4 rv = reinterpret_cast<const float4*>(rs + (size_t)i * DDIM)[il];
    float c0 = e.x + rv.x, c1 = e.y + rv.y, c2 = e.z + rv.z, c3 = e.w + rv.w;
    ushort4 h4; h4.x = f2bf(c0); h4.y = f2bf(c1); h4.z = f2bf(c2); h4.w = f2bf(c3);
    reinterpret_cast<ushort4*>(c_bf + (size_t)row * DDIM)[il] = h4;
    float sq = fmaf(c0, c0, fmaf(c1, c1, fmaf(c2, c2, c3 * c3)));
    #pragma unroll
    for (int m = 1; m <= 16; m <<= 1) sq += __shfl_xor(sq, m);
    if (il == 0) cnorm[row] = sq;
    if (br == 0) {
      int t = pos_t[i];
      float4 et = reinterpret_cast<const float4*>(ent + (size_t)t * DDIM)[il];
      float d0 = c0 - et.x, d1 = c1 - et.y, d2v = c2 - et.z, d3 = c3 - et.w;
      float d2 = fmaf(d0, d0, fmaf(d1, d1, fmaf(d2v, d2v, d3 * d3)));
      float m1 = fabsf(d0) + fabsf(d1) + fabsf(d2v) + fabsf(d3);
      #pragma unroll
      for (int m = 1; m <= 16; m <<= 1) { d2 += __shfl_xor(d2, m); m1 += __shfl_xor(m1, m); }
      if (il == 0) {
        float s = (*l1_flag) ? (100.f / fmaxf(m1, 1e-12f))
                             : (100.f * rsqrtf(fmaxf(d2, 0.f)));  // d2=0 -> inf, clamps ok
        float x  = __expf(-s);
        float L  = log1pf(x);
        float Bt = fminf(-L, LP_MAX);          // exact log(pred)
        float Ap = fmaxf(-s, -S_CLAMP);        // what main_k adds for this element
        tpart[i] = Bt - Ap;
      }
    }
  }
}

// Main: R10 body verbatim (63 µs measured; best) + 4-way lsum accumulators.
// XCD-aware 1D swizzle: jt = (id&7) + 8*(id>>7 grouping); the 16 blocks
// sharing a j-tile all have id == jt (mod 8) -> one XCD -> tile fetched once
// per L2 (verified R10: FETCH 41->7 MB). Padded grid 5120; jt>=313 exits
// pre-barrier. One pass/block, 128x128 tile, 2x2 waves, 4x4 MFMA tiles;
// B tile via global_load_lds w=16 (async DMA — R11 proved sync staging costs
// ~25 µs), XOR chunk swizzle (0 conflicts); A frags direct from L2-hot c_bf,
// dbuf over kc. Natural register allocation. NO fused finalize (R7: device
// fences at 5k blocks cost ~90 µs). 5-inst epilogue in u-units; tpart fixup
// replaces the per-element target check.
__global__ __launch_bounds__(256) void main_k(const unsigned short* __restrict__ c_bf,
                                              const unsigned short* __restrict__ ent_bf,
                                              const float* __restrict__ cnorm,
                                              const float* __restrict__ enorm,
                                              const int* __restrict__ l1_flag,
                                              const int* __restrict__ pos_h,
                                              const int* __restrict__ neg_h,
                                              const float* __restrict__ rpos,
                                              const float* __restrict__ rneg,
                                              const float* __restrict__ ent_f32,
                                              float* __restrict__ partials) {
  __shared__ unsigned short smem[128 * 128];    // 32 KB swizzled B tile
  const int id = blockIdx.x;
  const int c8 = id & 7;
  const int q  = id >> 3;
  const int tg = q >> 4;                         // 0..39
  const int mm = q & 15;                         // member 0..15
  const int jt = c8 + tg * 8;                    // 0..319
  if (jt >= NJT) return;                         // block-uniform, pre-barrier
  const int branch = mm & 1;
  const int it = mm >> 1;                        // 0..7
  const int i0 = it * 128, j0 = jt * 128;
  const int tid = threadIdx.x, lane = tid & 63, wv = tid >> 6;
  const int wm = wv >> 1, wn = wv & 1;
  const int r15 = lane & 15, quad = lane >> 4;

  // ---- async stage B tile: 2048 x 16B chunks, swizzled c' = c ^ (row&15) ----
  #pragma unroll
  for (int i = 0; i < 8; ++i) {
    int g  = i * 256 + tid;        // LDS dst = uniform base + lane*16 (m104 rule)
    int r  = g >> 4;
    int cp = g & 15;
    int c  = cp ^ (r & 15);
    int jr = j0 + r; if (jr >= N_ENT) jr = N_ENT - 1;   // clamp; masked in epilogue
    const unsigned short* src = ent_bf + (size_t)jr * DDIM + c * 8;
    __builtin_amdgcn_global_load_lds((const AS1 void*)src, (AS3 void*)(&smem[g * 8]), 16, 0, 0);
  }

  // ---- A fragment pointers + prefetch kc=0; preload norms (hide L2 latency) ----
  const unsigned short* Abase = c_bf + ((size_t)(branch << 10) + i0) * DDIM;
  const unsigned short* arow[4];
  #pragma unroll
  for (int tm = 0; tm < 4; ++tm)
    arow[tm] = Abase + (size_t)(wm * 64 + tm * 16 + r15) * DDIM + quad * 8;

  s16x8 av[2][4];
  #pragma unroll
  for (int tm = 0; tm < 4; ++tm)
    av[0][tm] = *reinterpret_cast<const s16x8*>(arow[tm]);

  float en[4];
  #pragma unroll
  for (int tn = 0; tn < 4; ++tn) {
    int jg = j0 + wn * 64 + tn * 16 + r15;
    en[tn] = enorm[jg < N_ENT ? jg : N_ENT - 1];
  }
  float cnv[16];
  #pragma unroll
  for (int tm = 0; tm < 4; ++tm)
    #pragma unroll
    for (int r = 0; r < 4; ++r)
      cnv[tm * 4 + r] = cnorm[(branch << 10) + i0 + wm * 64 + tm * 16 + quad * 4 + r];

  f32x4 acc[4][4];
  const f32x4 zf = {0.f, 0.f, 0.f, 0.f};
  #pragma unroll
  for (int a = 0; a < 4; ++a)
    #pragma unroll
    for (int b = 0; b < 4; ++b) acc[a][b] = zf;

  __syncthreads();   // drains vmcnt: B tile staged (A kc0 + norms also landed)

  #pragma unroll
  for (int kc = 0; kc < 4; ++kc) {
    if (kc < 3) {
      #pragma unroll
      for (int tm = 0; tm < 4; ++tm)
        av[(kc + 1) & 1][tm] = *reinterpret_cast<const s16x8*>(arow[tm] + (kc + 1) * 32);
    }
    s16x8 bv[4];
    #pragma unroll
    for (int tn = 0; tn < 4; ++tn) {
      int R  = wn * 64 + tn * 16 + r15;
      int cs = (kc * 4 + quad) ^ r15;
      bv[tn] = *reinterpret_cast<const s16x8*>(&smem[R * 128 + cs * 8]);
    }
    #pragma unroll
    for (int tm = 0; tm < 4; ++tm)
      #pragma unroll
      for (int tn = 0; tn < 4; ++tn)
        acc[tm][tn] = __builtin_amdgcn_mfma_f32_16x16x32_bf16(av[kc & 1][tm], bv[tn], acc[tm][tn], 0, 0, 0);
  }

  // ---- 5-inst epilogue: fma, rsqrt, fmin, add (in u-units), 4 accumulators ----
  const int l1 = *l1_flag;
  float ls0 = 0.f, ls1 = 0.f, ls2 = 0.f, ls3 = 0.f;
  const bool full = (j0 + 128) <= N_ENT;   // block-uniform

  if (!l1) {
    #pragma unroll
    for (int tm = 0; tm < 4; ++tm) {
      if (full) {
        #pragma unroll
        for (int tn = 0; tn < 4; ++tn) {
          float e0 = en[tn];
          float u0 = rsqrtf(fmaf(-2.f, acc[tm][tn][0], cnv[tm * 4 + 0] + e0));
          float u1 = rsqrtf(fmaf(-2.f, acc[tm][tn][1], cnv[tm * 4 + 1] + e0));
          float u2 = rsqrtf(fmaf(-2.f, acc[tm][tn][2], cnv[tm * 4 + 2] + e0));
          float u3 = rsqrtf(fmaf(-2.f, acc[tm][tn][3], cnv[tm * 4 + 3] + e0));
          ls0 += fminf(u0, U_CLAMP);         // <=0/NaN -> fmin clamps
          ls1 += fminf(u1, U_CLAMP);
          ls2 += fminf(u2, U_CLAMP);
          ls3 += fminf(u3, U_CLAMP);
        }
      } else {
        #pragma unroll
        for (int tn = 0; tn < 4; ++tn) {
          int jg = j0 + wn * 64 + tn * 16 + r15;
          if (jg < N_ENT) {
            float e0 = en[tn];
            ls0 += fminf(rsqrtf(fmaf(-2.f, acc[tm][tn][0], cnv[tm * 4 + 0] + e0)), U_CLAMP);
            ls1 += fminf(rsqrtf(fmaf(-2.f, acc[tm][tn][1], cnv[tm * 4 + 1] + e0)), U_CLAMP);
            ls2 += fminf(rsqrtf(fmaf(-2.f, acc[tm][tn][2], cnv[tm * 4 + 2] + e0)), U_CLAMP);
            ls3 += fminf(rsqrtf(fmaf(-2.f, acc[tm][tn][3], cnv[tm * 4 + 3] + e0)), U_CLAMP);
          }
        }
      }
    }
  } else {
    // L1 fallback (dead with this harness's inputs): recompute on the fly.
    const float* rs = branch ? rneg : rpos;
    const int*   hb = branch ? neg_h : pos_h;
    #pragma unroll 1
    for (int tm = 0; tm < 4; ++tm) {
      #pragma unroll 1
      for (int r = 0; r < 4; ++r) {
        int bi = i0 + wm * 64 + tm * 16 + quad * 4 + r;
        int h  = hb[bi];
        #pragma unroll 1
        for (int tn = 0; tn < 4; ++tn) {
          int jg = j0 + wn * 64 + tn * 16 + r15;
          if (jg < N_ENT) {
            const float* cp1 = ent_f32 + (size_t)h * DDIM;
            const float* cp2 = rs + (size_t)bi * DDIM;
            const float* ep  = ent_f32 + (size_t)jg * DDIM;
            float man = 0.f;
            #pragma unroll 1
            for (int d = 0; d < DDIM; ++d) man += fabsf(cp1[d] + cp2[d] - ep[d]);
            float s = 100.f / fmaxf(man, 1e-12f);
            ls0 += 0.01f * fminf(s, S_CLAMP);   // same u-unit scale
          }
        }
      }
    }
  }
  float lsum = (ls0 + ls1) + (ls2 + ls3);

  // block reduction -> one partial per block (no atomics, no fences)
  #pragma unroll
  for (int m = 32; m; m >>= 1) lsum += __shfl_xor(lsum, m);
  __shared__ float s4[4];
  if (lane == 0) s4[wv] = lsum;
  __syncthreads();
  if (tid == 0)
    partials[jt * 16 + mm] = s4[0] + s4[1] + s4[2] + s4[3];
}

// Parallel finalize: 24 blocks, one element per thread, f32 atomic into the
// memset-zeroed d_out. Blocks [0,20): partials (x 100/(B*N)); [20,24): tpart
// (x -1/(B*N)). ~24 atomics to one address: trivial contention.
__global__ __launch_bounds__(256) void finalize_k(const float* __restrict__ partials,
                                                  const float* __restrict__ tpart,
                                                  float* __restrict__ out) {
  const int b = blockIdx.x, tid = threadIdx.x, lane = tid & 63, wv = tid >> 6;
  const double inv = 1.0 / ((double)BSZ * (double)N_ENT);
  double v = 0.0;
  if (b < 20) {
    int i = b * 256 + tid;
    if (i < NPART) v = (double)partials[i] * (100.0 * inv);
  } else {
    int i = (b - 20) * 256 + tid;
    v = (double)tpart[i] * (-inv);
  }
  #pragma unroll
  for (int m = 32; m; m >>= 1) v += __shfl_xor(v, m);
  __shared__ double sd[4];
  if (lane == 0) sd[wv] = v;
  __syncthreads();
  if (tid == 0) atomicAdd(out, (float)(sd[0] + sd[1] + sd[2] + sd[3]));
}

extern "C" void kernel_launch(void* const* d_in, const int* in_sizes, int n_in,
                              void* d_out, int out_size, void* d_ws, size_t ws_size,
                              hipStream_t stream) {
  const int*   pos_h = (const int*)d_in[0];
  const int*   pos_t = (const int*)d_in[1];
  const int*   neg_h = (const int*)d_in[2];
  // d_in[3] = neg_t_batch (unused by reference)
  const float* rpos  = (const float*)d_in[4];
  const float* rneg  = (const float*)d_in[5];
  const float* ent   = (const float*)d_in[6];
  const int*   l1    = (const int*)d_in[7];

  char* ws = (char*)d_ws;
  float*          partials = (float*)(ws + OFF_PART);
  float*          tpart    = (float*)(ws + OFF_TPART);
  float*          enorm    = (float*)(ws + OFF_ENORM);
  float*          cnorm    = (float*)(ws + OFF_CNORM);
  unsigned short* c_bf     = (unsigned short*)(ws + OFF_CBF);
  unsigned short* ent_bf   = (unsigned short*)(ws + OFF_EBF);

  hipMemsetAsync(d_out, 0, sizeof(float), stream);   // finalize accumulates atomically

  prep_k<<<5256, 256, 0, stream>>>(ent, pos_h, pos_t, neg_h, rpos, rneg, l1,
                                   ent_bf, enorm, c_bf, cnorm, tpart);

  main_k<<<NGRID, 256, 0, stream>>>(c_bf, ent_bf, cnorm, enorm, l1,
                                    pos_h, neg_h, rpos, rneg, ent, partials);

  finalize_k<<<24, 256, 0, stream>>>(partials, tpart, (float*)d_out);
}